// Round 7
// baseline (221.260 us; speedup 1.0000x reference)
//
#include <hip/hip_runtime.h>

#define N_NODES 10000
#define N_EDGES 160000
#define FNODE 8
#define FEDGE 4
#define C 24
#define NITER 4
#define HID 16
#define NB_HEAD 60
#define TW (5 * C)   // 120: per-node T row = [f=0..3: ea-weighted parts][f=4: bias part]
#define NPB 16       // nodes per block in layer kernel; 625*16 == 10000 exactly

// Module-owned scratch: immune to d_ws poisoning / ws_size limits. Fully
// rebuilt every call (no caching), so every call does identical work.
__device__ float g_TA[N_NODES * TW];
__device__ float g_TB[N_NODES * TW];
__device__ float g_hA[N_NODES * C];
__device__ float g_hB[N_NODES * C];
__device__ int   g_deg[N_NODES];        // degree, then reused as scatter cursor
__device__ int   g_off[N_NODES + 1];    // CSR offsets (incoming edges per dst)
__device__ int   g_eidx[N_EDGES];       // CSR edge ids
__device__ float g_partial[NB_HEAD * HID];

// ---------- CSR build (per call; order within a node nondeterministic, but
// ---------- downstream max-aggregation is order-invariant) ----------
__global__ void csr_zero_kernel() {
    const int n = blockIdx.x * blockDim.x + threadIdx.x;
    if (n < N_NODES) g_deg[n] = 0;
}
__global__ void csr_hist_kernel(const int* __restrict__ dst) {
    const int e = blockIdx.x * blockDim.x + threadIdx.x;
    if (e < N_EDGES) atomicAdd(&g_deg[dst[e]], 1);
}
#define SCAN_T 1024
#define SCAN_I 10   // 1024*10 = 10240 >= 10000
__global__ void csr_scan_kernel() {
    __shared__ int s[SCAN_T];
    const int tid = threadIdx.x;
    const int base = tid * SCAN_I;
    int v[SCAN_I];
    int tot = 0;
#pragma unroll
    for (int j = 0; j < SCAN_I; ++j) {
        const int idx = base + j;
        v[j] = (idx < N_NODES) ? g_deg[idx] : 0;
        tot += v[j];
    }
    s[tid] = tot;
    __syncthreads();
    for (int off = 1; off < SCAN_T; off <<= 1) {
        const int t = (tid >= off) ? s[tid - off] : 0;
        __syncthreads();
        s[tid] += t;
        __syncthreads();
    }
    int run = s[tid] - tot;  // exclusive prefix of this thread's chunk
#pragma unroll
    for (int j = 0; j < SCAN_I; ++j) {
        const int idx = base + j;
        if (idx < N_NODES) { g_off[idx] = run; g_deg[idx] = run; }  // deg -> cursor
        run += v[j];
    }
    if (tid == 0) g_off[N_NODES] = N_EDGES;
}
__global__ void csr_scatter_kernel(const int* __restrict__ dst) {
    const int e = blockIdx.x * blockDim.x + threadIdx.x;
    if (e < N_EDGES) {
        const int p = atomicAdd(&g_deg[dst[e]], 1);
        g_eidx[p] = e;
    }
}

// ---------- T projection for layer 0 (from x, IN_C=8) ----------
// T[n][f*C+o] = sum_i h[n][i]*W[f][i*C+o] (f<4); T[n][4*C+o] = sum_i h[n][i]*b[i*C+o].
template <int IN_C, int TNPB>
__global__ void tmat_kernel(const float* __restrict__ h,
                            const float* __restrict__ W,
                            const float* __restrict__ b,
                            float* __restrict__ T) {
    __shared__ float sW_t[IN_C * TW];
    __shared__ float sh[TNPB][IN_C];
    const int tid = threadIdx.x + threadIdx.y * TW;
    const int nthr = TW * TNPB;
    for (int idx = tid; idx < IN_C * TW; idx += nthr) {
        const int i = idx / TW;
        const int x = idx - i * TW;
        const int f = x / C;
        const int o = x - f * C;
        sW_t[idx] = (f < 4) ? W[f * IN_C * C + i * C + o] : b[i * C + o];
    }
    const int n = blockIdx.x * TNPB + threadIdx.y;
    if (n < N_NODES && threadIdx.x < IN_C)
        sh[threadIdx.y][threadIdx.x] = h[n * IN_C + threadIdx.x];
    __syncthreads();
    if (n >= N_NODES) return;
    const int x = threadIdx.x;
    float acc = 0.f;
#pragma unroll
    for (int i = 0; i < IN_C; ++i)
        acc = fmaf(sh[threadIdx.y][i], sW_t[i * TW + x], acc);
    T[n * TW + x] = acc;
}

// ---------- Fused layer: edge max-gather + node update (+ next-layer T) ----------
// Block (C, NPB); node n owned by y-slot. Per in-edge: msg[o] = T4[src][o] +
// sum_f ea[f]*Tf[src][o]; agg = max (0 if no edges). h = relu6(agg + h_in@root
// + bias). If HAS_NEXT: T_out[n] = proj(h; Wn, bn) via LDS-staged transpose.
template <int IN_C, bool HAS_NEXT>
__global__ void layer_kernel(const float* __restrict__ T_in,
                             const float* __restrict__ h_in,
                             const float* __restrict__ ea,   // [E][4]
                             const int* __restrict__ src,
                             const float* __restrict__ root, // [IN_C][C]
                             const float* __restrict__ bias, // [C]
                             const float* __restrict__ Wn,   // [4][C*C] (next T)
                             const float* __restrict__ bn,   // [C*C]
                             float* __restrict__ h_out,
                             float* __restrict__ T_out) {
    __shared__ float sWt[HAS_NEXT ? C * TW : 1];
    __shared__ float sroot[IN_C * C];
    __shared__ float sbias[C];
    __shared__ float shin[NPB][IN_C];
    __shared__ float shh[NPB][C];

    const int o = threadIdx.x;
    const int y = threadIdx.y;
    const int tid = o + C * y;
    const int nthr = C * NPB;
    if (HAS_NEXT) {
        for (int idx = tid; idx < C * TW; idx += nthr) {
            const int i = idx / TW;
            const int x = idx - i * TW;
            const int f = x / C;
            const int oo = x - f * C;
            sWt[idx] = (f < 4) ? Wn[f * C * C + i * C + oo] : bn[i * C + oo];
        }
    }
    for (int idx = tid; idx < IN_C * C; idx += nthr) sroot[idx] = root[idx];
    if (tid < C) sbias[tid] = bias[tid];
    const int n = blockIdx.x * NPB + y;   // grid*NPB == N_NODES exactly
    if (o < IN_C) shin[y][o] = h_in[n * IN_C + o];
    __syncthreads();

    const int ks = g_off[n];
    const int ke = g_off[n + 1];
    float acc = -INFINITY;
    // hand-pipelined: prefetch next edge's (eidx, ea, src) during current T reads
    int e_cur = 0, s_cur = 0;
    float4 a_cur = make_float4(0.f, 0.f, 0.f, 0.f);
    if (ks < ke) {
        e_cur = g_eidx[ks];
        a_cur = ((const float4*)ea)[e_cur];
        s_cur = src[e_cur];
    }
    for (int k = ks; k < ke; ++k) {
        const float* Tr = T_in + (size_t)s_cur * TW;
        int e_nxt = 0, s_nxt = 0;
        float4 a_nxt = a_cur;
        if (k + 1 < ke) {
            e_nxt = g_eidx[k + 1];
            a_nxt = ((const float4*)ea)[e_nxt];
            s_nxt = src[e_nxt];
        }
        float m = Tr[4 * C + o];
        m = fmaf(a_cur.x, Tr[0 * C + o], m);
        m = fmaf(a_cur.y, Tr[1 * C + o], m);
        m = fmaf(a_cur.z, Tr[2 * C + o], m);
        m = fmaf(a_cur.w, Tr[3 * C + o], m);
        acc = fmaxf(acc, m);
        e_cur = e_nxt; a_cur = a_nxt; s_cur = s_nxt;
    }
    const float agg = (ks == ke) ? 0.f : acc;

    float r = sbias[o];
#pragma unroll
    for (int i = 0; i < IN_C; ++i) r = fmaf(shin[y][i], sroot[i * C + o], r);
    const float h = fminf(fmaxf(agg + r, 0.f), 6.f);
    h_out[n * C + o] = h;

    if (HAS_NEXT) {
        shh[y][o] = h;
        __syncthreads();
#pragma unroll
        for (int f = 0; f < 5; ++f) {
            const int x = f * C + o;
            float t = 0.f;
#pragma unroll
            for (int i = 0; i < C; ++i) t = fmaf(shh[y][i], sWt[i * TW + x], t);
            T_out[n * TW + x] = t;
        }
    }
}

// ---------- Output head (deterministic two-stage GEMV) ----------
__global__ void head1_kernel(const float* __restrict__ h,
                             const float* __restrict__ w1,
                             float* __restrict__ partial) {
    __shared__ float s[256 * HID];
    float acc[HID];
#pragma unroll
    for (int j = 0; j < HID; ++j) acc[j] = 0.f;
    for (int k = blockIdx.x * blockDim.x + threadIdx.x; k < N_NODES * C;
         k += gridDim.x * blockDim.x) {
        const float f = h[k];
        const float4* wp = (const float4*)(w1 + (size_t)k * HID);
#pragma unroll
        for (int q = 0; q < 4; ++q) {
            const float4 w = wp[q];
            acc[q * 4 + 0] = fmaf(f, w.x, acc[q * 4 + 0]);
            acc[q * 4 + 1] = fmaf(f, w.y, acc[q * 4 + 1]);
            acc[q * 4 + 2] = fmaf(f, w.z, acc[q * 4 + 2]);
            acc[q * 4 + 3] = fmaf(f, w.w, acc[q * 4 + 3]);
        }
    }
#pragma unroll
    for (int j = 0; j < HID; ++j) s[threadIdx.x * HID + j] = acc[j];
    __syncthreads();
    for (int off = 128; off > 0; off >>= 1) {
        if (threadIdx.x < off) {
#pragma unroll
            for (int j = 0; j < HID; ++j)
                s[threadIdx.x * HID + j] += s[(threadIdx.x + off) * HID + j];
        }
        __syncthreads();
    }
    if (threadIdx.x < HID) partial[blockIdx.x * HID + threadIdx.x] = s[threadIdx.x];
}

__global__ void head2_kernel(const float* __restrict__ partial,
                             const float* __restrict__ b1,
                             const float* __restrict__ w2,
                             const float* __restrict__ b2,
                             float* __restrict__ out) {
    __shared__ float hid[HID];
    const int j = threadIdx.x;
    if (j < HID) {
        float a = b1[j];
        for (int bidx = 0; bidx < NB_HEAD; ++bidx) a += partial[bidx * HID + j];
        hid[j] = (a > 0.f) ? a : expm1f(a);
    }
    __syncthreads();
    if (j == 0) {
        float a = b2[0];
#pragma unroll
        for (int q = 0; q < HID; ++q) a += hid[q] * w2[q];
        out[0] = (a > 0.f) ? a : expm1f(a);
    }
}

extern "C" void kernel_launch(void* const* d_in, const int* in_sizes, int n_in,
                              void* d_out, int out_size, void* d_ws, size_t ws_size,
                              hipStream_t stream) {
    const float* x      = (const float*)d_in[0];
    const float* ea     = (const float*)d_in[1];
    const int*   ei     = (const int*)d_in[2];
    const float* few    = (const float*)d_in[3];
    const float* feb    = (const float*)d_in[4];
    const float* ew     = (const float*)d_in[5];
    const float* ebias  = (const float*)d_in[6];
    const float* root0  = (const float*)d_in[7];
    const float* bias0  = (const float*)d_in[8];
    const float* roots  = (const float*)d_in[9];
    const float* biases = (const float*)d_in[10];
    const float* w1     = (const float*)d_in[11];
    const float* b1     = (const float*)d_in[12];
    const float* w2     = (const float*)d_in[13];
    const float* b2     = (const float*)d_in[14];
    float* out = (float*)d_out;

    const int* src = ei;
    const int* dst = ei + N_EDGES;

    void *pTA_, *pTB_, *pA_, *pB_, *pPart_;
    hipGetSymbolAddress(&pTA_, HIP_SYMBOL(g_TA));
    hipGetSymbolAddress(&pTB_, HIP_SYMBOL(g_TB));
    hipGetSymbolAddress(&pA_,  HIP_SYMBOL(g_hA));
    hipGetSymbolAddress(&pB_,  HIP_SYMBOL(g_hB));
    hipGetSymbolAddress(&pPart_, HIP_SYMBOL(g_partial));
    float* TA = (float*)pTA_;
    float* TB = (float*)pTB_;
    float* hA = (float*)pA_;
    float* hB = (float*)pB_;
    float* partial = (float*)pPart_;

    // CSR build (4 small dispatches)
    csr_zero_kernel<<<(N_NODES + 255) / 256, 256, 0, stream>>>();
    csr_hist_kernel<<<(N_EDGES + 255) / 256, 256, 0, stream>>>(dst);
    csr_scan_kernel<<<1, SCAN_T, 0, stream>>>();
    csr_scatter_kernel<<<(N_EDGES + 255) / 256, 256, 0, stream>>>(dst);

    // T for layer 0 from x
    dim3 tblk(TW, 8);
    tmat_kernel<FNODE, 8><<<(N_NODES + 7) / 8, tblk, 0, stream>>>(x, few, feb, TA);

    dim3 lblk(C, NPB);
    const int lgrid = N_NODES / NPB;  // 625, exact
    // L0: reads TA,x; writes h1=hA, TB=proj(h1)
    layer_kernel<FNODE, true><<<lgrid, lblk, 0, stream>>>(
        TA, x, ea, src, root0, bias0, ew, ebias, hA, TB);
    // iter 0: reads TB,hA; writes h2=hB, TA
    layer_kernel<C, true><<<lgrid, lblk, 0, stream>>>(
        TB, hA, ea, src, roots + 0 * C * C, biases + 0 * C, ew, ebias, hB, TA);
    // iter 1: reads TA,hB; writes h3=hA, TB
    layer_kernel<C, true><<<lgrid, lblk, 0, stream>>>(
        TA, hB, ea, src, roots + 1 * C * C, biases + 1 * C, ew, ebias, hA, TB);
    // iter 2: reads TB,hA; writes h4=hB, TA
    layer_kernel<C, true><<<lgrid, lblk, 0, stream>>>(
        TB, hA, ea, src, roots + 2 * C * C, biases + 2 * C, ew, ebias, hB, TA);
    // iter 3 (last): reads TA,hB; writes h5=hA, no T
    layer_kernel<C, false><<<lgrid, lblk, 0, stream>>>(
        TA, hB, ea, src, roots + 3 * C * C, biases + 3 * C, ew, ebias, hA, TB);

    head1_kernel<<<NB_HEAD, 256, 0, stream>>>(hA, w1, partial);
    head2_kernel<<<1, 64, 0, stream>>>(partial, b1, w2, b2, out);
}

// Round 9
// 152.797 us; speedup vs baseline: 1.4481x; 1.4481x over previous
//
#include <hip/hip_runtime.h>

#define N_NODES 10000
#define N_EDGES 160000
#define FNODE 8
#define FEDGE 4
#define C 24
#define NITER 4
#define HID 16
#define NB_HEAD 60
#define TW (5 * C)   // 120: per-node T row = [f=0..3: ea-weighted parts][f=4: bias part]
#define NPB 16       // nodes per block in layer kernel; 625*16 == 10000 exactly

// Module-owned scratch: immune to d_ws poisoning / ws_size limits. Fully
// rebuilt every call (no caching), so every call does identical work.
__device__ float  g_TA[N_NODES * TW];
__device__ float  g_TB[N_NODES * TW];
__device__ float  g_hA[N_NODES * C];
__device__ float  g_hB[N_NODES * C];
__device__ int    g_deg[N_NODES];        // degree, then reused as scatter cursor
__device__ int    g_off[N_NODES + 1];    // CSR offsets (incoming edges per dst)
__device__ int    g_csr_src[N_EDGES];    // src node id, CSR order
__device__ float4 g_csr_ea[N_EDGES];     // edge attr, CSR order
__device__ float  g_partial[NB_HEAD * HID];

// ---------- CSR build (per call; order within a node nondeterministic, but
// ---------- downstream max-aggregation is order-invariant) ----------
__global__ void csr_zero_kernel() {
    const int n = blockIdx.x * blockDim.x + threadIdx.x;
    if (n < N_NODES) g_deg[n] = 0;
}
__global__ void csr_hist_kernel(const int* __restrict__ dst) {
    const int e = blockIdx.x * blockDim.x + threadIdx.x;
    if (e < N_EDGES) atomicAdd(&g_deg[dst[e]], 1);
}
#define SCAN_T 1024
#define SCAN_I 10   // 1024*10 = 10240 >= 10000
__global__ void csr_scan_kernel() {
    __shared__ int s[SCAN_T];
    const int tid = threadIdx.x;
    const int base = tid * SCAN_I;
    int v[SCAN_I];
    int tot = 0;
#pragma unroll
    for (int j = 0; j < SCAN_I; ++j) {
        const int idx = base + j;
        v[j] = (idx < N_NODES) ? g_deg[idx] : 0;
        tot += v[j];
    }
    s[tid] = tot;
    __syncthreads();
    for (int off = 1; off < SCAN_T; off <<= 1) {
        const int t = (tid >= off) ? s[tid - off] : 0;
        __syncthreads();
        s[tid] += t;
        __syncthreads();
    }
    int run = s[tid] - tot;  // exclusive prefix of this thread's chunk
#pragma unroll
    for (int j = 0; j < SCAN_I; ++j) {
        const int idx = base + j;
        if (idx < N_NODES) { g_off[idx] = run; g_deg[idx] = run; }  // deg -> cursor
        run += v[j];
    }
    if (tid == 0) g_off[N_NODES] = N_EDGES;
}
// Scatter edge id -> CSR slot, materializing src + ea in CSR order so the hot
// loop has NO eidx indirection.
__global__ void csr_scatter_kernel(const int* __restrict__ src,
                                   const int* __restrict__ dst,
                                   const float* __restrict__ ea) {
    const int e = blockIdx.x * blockDim.x + threadIdx.x;
    if (e < N_EDGES) {
        const int p = atomicAdd(&g_deg[dst[e]], 1);
        g_csr_src[p] = src[e];
        const float4 a = ((const float4*)ea)[e];
        g_csr_ea[p] = a;
    }
}

// ---------- T projection for layer 0 (from x, IN_C=8) ----------
template <int IN_C, int TNPB>
__global__ void tmat_kernel(const float* __restrict__ h,
                            const float* __restrict__ W,
                            const float* __restrict__ b,
                            float* __restrict__ T) {
    __shared__ float sW_t[IN_C * TW];
    __shared__ float sh[TNPB][IN_C];
    const int tid = threadIdx.x + threadIdx.y * TW;
    const int nthr = TW * TNPB;
    for (int idx = tid; idx < IN_C * TW; idx += nthr) {
        const int i = idx / TW;
        const int x = idx - i * TW;
        const int f = x / C;
        const int o = x - f * C;
        sW_t[idx] = (f < 4) ? W[f * IN_C * C + i * C + o] : b[i * C + o];
    }
    const int n = blockIdx.x * TNPB + threadIdx.y;
    if (n < N_NODES && threadIdx.x < IN_C)
        sh[threadIdx.y][threadIdx.x] = h[n * IN_C + threadIdx.x];
    __syncthreads();
    if (n >= N_NODES) return;
    const int x = threadIdx.x;
    float acc = 0.f;
#pragma unroll
    for (int i = 0; i < IN_C; ++i)
        acc = fmaf(sh[threadIdx.y][i], sW_t[i * TW + x], acc);
    T[n * TW + x] = acc;
}

// ---------- Fused layer: edge max-gather + node update (+ next-layer T) ----------
// Block (C, NPB); node n owned by y-slot. Edge loop: only ONE dependent load
// level (csr_src[k] -> T row); csr_src/csr_ea are sequential. unroll(4) keeps
// 4 independent chains in flight. fmax is order-invariant -> bit-stable.
template <int IN_C, bool HAS_NEXT>
__global__ void layer_kernel(const float* __restrict__ T_in,
                             const float* __restrict__ h_in,
                             const float* __restrict__ root, // [IN_C][C]
                             const float* __restrict__ bias, // [C]
                             const float* __restrict__ Wn,   // [4][C*C] (next T)
                             const float* __restrict__ bn,   // [C*C]
                             float* __restrict__ h_out,
                             float* __restrict__ T_out) {
    __shared__ float sWt[HAS_NEXT ? C * TW : 1];
    __shared__ float sroot[IN_C * C];
    __shared__ float sbias[C];
    __shared__ float shin[NPB][IN_C];
    __shared__ float shh[NPB][C];

    const int o = threadIdx.x;
    const int y = threadIdx.y;
    const int tid = o + C * y;
    const int nthr = C * NPB;
    if (HAS_NEXT) {
        for (int idx = tid; idx < C * TW; idx += nthr) {
            const int i = idx / TW;
            const int x = idx - i * TW;
            const int f = x / C;
            const int oo = x - f * C;
            sWt[idx] = (f < 4) ? Wn[f * C * C + i * C + oo] : bn[i * C + oo];
        }
    }
    for (int idx = tid; idx < IN_C * C; idx += nthr) sroot[idx] = root[idx];
    if (tid < C) sbias[tid] = bias[tid];
    const int n = blockIdx.x * NPB + y;   // grid*NPB == N_NODES exactly
    if (o < IN_C) shin[y][o] = h_in[n * IN_C + o];
    __syncthreads();

    const int ks = g_off[n];
    const int ke = g_off[n + 1];
    float acc = -INFINITY;
#pragma unroll 4
    for (int k = ks; k < ke; ++k) {
        const int s = g_csr_src[k];        // sequential load, uniform per y-slot
        const float4 a = g_csr_ea[k];      // sequential load
        const float* __restrict__ Tr = T_in + (size_t)s * TW;
        float m = Tr[4 * C + o];
        m = fmaf(a.x, Tr[0 * C + o], m);
        m = fmaf(a.y, Tr[1 * C + o], m);
        m = fmaf(a.z, Tr[2 * C + o], m);
        m = fmaf(a.w, Tr[3 * C + o], m);
        acc = fmaxf(acc, m);
    }
    const float agg = (ks == ke) ? 0.f : acc;

    float r = sbias[o];
#pragma unroll
    for (int i = 0; i < IN_C; ++i) r = fmaf(shin[y][i], sroot[i * C + o], r);
    const float h = fminf(fmaxf(agg + r, 0.f), 6.f);
    h_out[n * C + o] = h;

    if (HAS_NEXT) {
        shh[y][o] = h;
        __syncthreads();
#pragma unroll
        for (int f = 0; f < 5; ++f) {
            const int x = f * C + o;
            float t = 0.f;
#pragma unroll
            for (int i = 0; i < C; ++i) t = fmaf(shh[y][i], sWt[i * TW + x], t);
            T_out[n * TW + x] = t;
        }
    }
}

// ---------- Output head (deterministic two-stage GEMV) ----------
__global__ void head1_kernel(const float* __restrict__ h,
                             const float* __restrict__ w1,
                             float* __restrict__ partial) {
    __shared__ float s[256 * HID];
    float acc[HID];
#pragma unroll
    for (int j = 0; j < HID; ++j) acc[j] = 0.f;
    for (int k = blockIdx.x * blockDim.x + threadIdx.x; k < N_NODES * C;
         k += gridDim.x * blockDim.x) {
        const float f = h[k];
        const float4* wp = (const float4*)(w1 + (size_t)k * HID);
#pragma unroll
        for (int q = 0; q < 4; ++q) {
            const float4 w = wp[q];
            acc[q * 4 + 0] = fmaf(f, w.x, acc[q * 4 + 0]);
            acc[q * 4 + 1] = fmaf(f, w.y, acc[q * 4 + 1]);
            acc[q * 4 + 2] = fmaf(f, w.z, acc[q * 4 + 2]);
            acc[q * 4 + 3] = fmaf(f, w.w, acc[q * 4 + 3]);
        }
    }
#pragma unroll
    for (int j = 0; j < HID; ++j) s[threadIdx.x * HID + j] = acc[j];
    __syncthreads();
    for (int off = 128; off > 0; off >>= 1) {
        if (threadIdx.x < off) {
#pragma unroll
            for (int j = 0; j < HID; ++j)
                s[threadIdx.x * HID + j] += s[(threadIdx.x + off) * HID + j];
        }
        __syncthreads();
    }
    if (threadIdx.x < HID) partial[blockIdx.x * HID + threadIdx.x] = s[threadIdx.x];
}

__global__ void head2_kernel(const float* __restrict__ partial,
                             const float* __restrict__ b1,
                             const float* __restrict__ w2,
                             const float* __restrict__ b2,
                             float* __restrict__ out) {
    __shared__ float hid[HID];
    const int j = threadIdx.x;
    if (j < HID) {
        float a = b1[j];
        for (int bidx = 0; bidx < NB_HEAD; ++bidx) a += partial[bidx * HID + j];
        hid[j] = (a > 0.f) ? a : expm1f(a);
    }
    __syncthreads();
    if (j == 0) {
        float a = b2[0];
#pragma unroll
        for (int q = 0; q < HID; ++q) a += hid[q] * w2[q];
        out[0] = (a > 0.f) ? a : expm1f(a);
    }
}

extern "C" void kernel_launch(void* const* d_in, const int* in_sizes, int n_in,
                              void* d_out, int out_size, void* d_ws, size_t ws_size,
                              hipStream_t stream) {
    const float* x      = (const float*)d_in[0];
    const float* ea     = (const float*)d_in[1];
    const int*   ei     = (const int*)d_in[2];
    const float* few    = (const float*)d_in[3];
    const float* feb    = (const float*)d_in[4];
    const float* ew     = (const float*)d_in[5];
    const float* ebias  = (const float*)d_in[6];
    const float* root0  = (const float*)d_in[7];
    const float* bias0  = (const float*)d_in[8];
    const float* roots  = (const float*)d_in[9];
    const float* biases = (const float*)d_in[10];
    const float* w1     = (const float*)d_in[11];
    const float* b1     = (const float*)d_in[12];
    const float* w2     = (const float*)d_in[13];
    const float* b2     = (const float*)d_in[14];
    float* out = (float*)d_out;

    const int* src = ei;
    const int* dst = ei + N_EDGES;

    void *pTA_, *pTB_, *pA_, *pB_, *pPart_;
    hipGetSymbolAddress(&pTA_, HIP_SYMBOL(g_TA));
    hipGetSymbolAddress(&pTB_, HIP_SYMBOL(g_TB));
    hipGetSymbolAddress(&pA_,  HIP_SYMBOL(g_hA));
    hipGetSymbolAddress(&pB_,  HIP_SYMBOL(g_hB));
    hipGetSymbolAddress(&pPart_, HIP_SYMBOL(g_partial));
    float* TA = (float*)pTA_;
    float* TB = (float*)pTB_;
    float* hA = (float*)pA_;
    float* hB = (float*)pB_;
    float* partial = (float*)pPart_;

    // CSR build (4 small dispatches)
    csr_zero_kernel<<<(N_NODES + 255) / 256, 256, 0, stream>>>();
    csr_hist_kernel<<<(N_EDGES + 255) / 256, 256, 0, stream>>>(dst);
    csr_scan_kernel<<<1, SCAN_T, 0, stream>>>();
    csr_scatter_kernel<<<(N_EDGES + 255) / 256, 256, 0, stream>>>(src, dst, ea);

    // T for layer 0 from x
    dim3 tblk(TW, 8);
    tmat_kernel<FNODE, 8><<<(N_NODES + 7) / 8, tblk, 0, stream>>>(x, few, feb, TA);

    dim3 lblk(C, NPB);
    const int lgrid = N_NODES / NPB;  // 625, exact
    layer_kernel<FNODE, true><<<lgrid, lblk, 0, stream>>>(
        TA, x, root0, bias0, ew, ebias, hA, TB);
    layer_kernel<C, true><<<lgrid, lblk, 0, stream>>>(
        TB, hA, roots + 0 * C * C, biases + 0 * C, ew, ebias, hB, TA);
    layer_kernel<C, true><<<lgrid, lblk, 0, stream>>>(
        TA, hB, roots + 1 * C * C, biases + 1 * C, ew, ebias, hA, TB);
    layer_kernel<C, true><<<lgrid, lblk, 0, stream>>>(
        TB, hA, roots + 2 * C * C, biases + 2 * C, ew, ebias, hB, TA);
    layer_kernel<C, false><<<lgrid, lblk, 0, stream>>>(
        TA, hB, roots + 3 * C * C, biases + 3 * C, ew, ebias, hA, TB);

    head1_kernel<<<NB_HEAD, 256, 0, stream>>>(hA, w1, partial);
    head2_kernel<<<1, 64, 0, stream>>>(partial, b1, w2, b2, out);
}